// Round 1
// baseline (778.707 us; speedup 1.0000x reference)
//
#include <hip/hip_runtime.h>
#include <stdint.h>

#define K_DIM 1024
#define N_DIM 1024

typedef __attribute__((ext_vector_type(8))) __bf16 bf16x8;
typedef __attribute__((ext_vector_type(4))) float f32x4;

// Static device storage (avoids d_ws size assumptions; fully rewritten every call)
__device__ __align__(16) unsigned short g_wq[N_DIM * K_DIM];  // ternary weights as bf16 bits
__device__ double g_partial[256];
__device__ float g_scale;

__device__ __forceinline__ unsigned int pack_bf16(float hi, float lo) {
  // (trunc_bf16(hi) << 16) | trunc_bf16(lo) in one v_perm_b32
  return __builtin_amdgcn_perm(__float_as_uint(hi), __float_as_uint(lo), 0x07060302u);
}

// ---- Kernel 1: partial sums of |w| (double accumulation, deterministic) ----
__global__ void absum_kernel(const float* __restrict__ w) {
  const int tid = threadIdx.x, bid = blockIdx.x;
  const float4* w4 = (const float4*)w;  // 262144 float4s total
  double s = 0.0;
#pragma unroll
  for (int i = 0; i < 4; i++) {
    float4 v = w4[bid * 1024 + i * 256 + tid];
    s += (double)fabsf(v.x) + (double)fabsf(v.y) + (double)fabsf(v.z) + (double)fabsf(v.w);
  }
#pragma unroll
  for (int o = 32; o > 0; o >>= 1) s += __shfl_down(s, o);
  __shared__ double sm[4];
  if ((tid & 63) == 0) sm[tid >> 6] = s;
  __syncthreads();
  if (tid == 0) g_partial[bid] = sm[0] + sm[1] + sm[2] + sm[3];
}

// ---- Kernel 2: final reduce -> scale = max(mean|w|, 1e-5) ----
__global__ void scale_kernel() {
  const int tid = threadIdx.x;
  double v = g_partial[tid];
#pragma unroll
  for (int o = 32; o > 0; o >>= 1) v += __shfl_down(v, o);
  __shared__ double sm[4];
  if ((tid & 63) == 0) sm[tid >> 6] = v;
  __syncthreads();
  if (tid == 0) {
    double total = sm[0] + sm[1] + sm[2] + sm[3];
    double mean = total * (1.0 / 1048576.0);  // exact pow2 divide
    g_scale = (float)fmax(mean, 1e-5);
  }
}

// ---- Kernel 3: quantize W -> ternary bf16 {-1,0,1} (exact in bf16) ----
__global__ void quant_kernel(const float* __restrict__ w) {
  const int idx = blockIdx.x * 256 + threadIdx.x;  // x4 floats
  const float s = g_scale;
  float4 v = ((const float4*)w)[idx];
  // IEEE divide + rintf (round-half-even) matches jnp.round(w/scale)
  float q0 = fminf(1.f, fmaxf(-1.f, rintf(v.x / s)));
  float q1 = fminf(1.f, fmaxf(-1.f, rintf(v.y / s)));
  float q2 = fminf(1.f, fmaxf(-1.f, rintf(v.z / s)));
  float q3 = fminf(1.f, fmaxf(-1.f, rintf(v.w / s)));
  ushort4 o;
  o.x = (unsigned short)(__float_as_uint(q0) >> 16);  // exact for -1,0,1
  o.y = (unsigned short)(__float_as_uint(q1) >> 16);
  o.z = (unsigned short)(__float_as_uint(q2) >> 16);
  o.w = (unsigned short)(__float_as_uint(q3) >> 16);
  ((ushort4*)g_wq)[idx] = o;
}

// ---- Kernel 4: GEMM  C[M,N] = (A[M,K] @ Wq[N,K]^T) * scale ----
// m97-style: 128x128 tile, BK=32, 4 waves (2x2), 4x4 MFMA 16x16x32 bf16 per wave.
__global__ __launch_bounds__(256) void bitlinear_gemm(const float* __restrict__ A,
                                                      float* __restrict__ C) {
  __shared__ __align__(16) unsigned short As[128 * 32];
  __shared__ __align__(16) unsigned short Bs[128 * 32];

  const int tid  = threadIdx.x;
  const int lane = tid & 63;
  const int wave = tid >> 6;
  const int wm   = (wave >> 1) * 64;  // wave row offset within tile
  const int wn   = (wave & 1) * 64;   // wave col offset within tile
  const int lm   = lane & 15;
  const int lq   = lane >> 4;

  const int n0 = blockIdx.x * 128;
  const int m0 = blockIdx.y * 128;

  f32x4 acc[4][4];
#pragma unroll
  for (int i = 0; i < 4; i++)
#pragma unroll
    for (int j = 0; j < 4; j++) acc[i][j] = (f32x4){0.f, 0.f, 0.f, 0.f};

  // A staging: thread t covers row t/2, 16 consecutive floats at k-offset (t&1)*16
  const int arow = tid >> 1;
  const int acol = (tid & 1) * 16;
  const float* aptr = A + (size_t)(m0 + arow) * K_DIM + acol;
  unsigned int* As_w = (unsigned int*)&As[tid * 16];  // byte offset tid*32

  // B staging via global_load_lds (wave-uniform LDS base + lane*16B):
  // wave instr i covers Bs rows [wave*32 + i*16, +16); lane l -> row +l/4, k-off (l&3)*8
  const unsigned short* bptr =
      g_wq + (size_t)(n0 + wave * 32 + (lane >> 2)) * K_DIM + (lane & 3) * 8;

  for (int kc = 0; kc < K_DIM; kc += 32) {
    __builtin_amdgcn_global_load_lds(
        (const __attribute__((address_space(1))) unsigned int*)(bptr + kc),
        (__attribute__((address_space(3))) unsigned int*)&Bs[(wave * 32) * 32],
        16, 0, 0);
    __builtin_amdgcn_global_load_lds(
        (const __attribute__((address_space(1))) unsigned int*)(bptr + 16 * K_DIM + kc),
        (__attribute__((address_space(3))) unsigned int*)&Bs[(wave * 32 + 16) * 32],
        16, 0, 0);

    const float4* ag = (const float4*)(aptr + kc);
    float4 v0 = ag[0], v1 = ag[1], v2 = ag[2], v3 = ag[3];
    uint4 p0, p1;
    p0.x = pack_bf16(v0.y, v0.x);
    p0.y = pack_bf16(v0.w, v0.z);
    p0.z = pack_bf16(v1.y, v1.x);
    p0.w = pack_bf16(v1.w, v1.z);
    p1.x = pack_bf16(v2.y, v2.x);
    p1.y = pack_bf16(v2.w, v2.z);
    p1.z = pack_bf16(v3.y, v3.x);
    p1.w = pack_bf16(v3.w, v3.z);
    ((uint4*)As_w)[0] = p0;
    ((uint4*)As_w)[1] = p1;

    __syncthreads();

    // Fragment loads: A[m=lane&15][k=(lane>>4)*8+j], B mirrors (bt layout)
    const bf16x8* Ap = (const bf16x8*)&As[(wm + lm) * 32 + lq * 8];
    const bf16x8* Bp = (const bf16x8*)&Bs[(wn + lm) * 32 + lq * 8];
    bf16x8 af[4], bf[4];
#pragma unroll
    for (int t = 0; t < 4; t++) {
      af[t] = Ap[t * 64];  // +16 rows per tile (16*32/8 = 64 x bf16x8)
      bf[t] = Bp[t * 64];
    }
#pragma unroll
    for (int mt = 0; mt < 4; mt++)
#pragma unroll
      for (int nt = 0; nt < 4; nt++)
        acc[mt][nt] =
            __builtin_amdgcn_mfma_f32_16x16x32_bf16(af[mt], bf[nt], acc[mt][nt], 0, 0, 0);

    __syncthreads();
  }

  // Epilogue: C/D layout col=lane&15, row=(lane>>4)*4+j; multiply by scale here
  const float s = g_scale;
#pragma unroll
  for (int mt = 0; mt < 4; mt++) {
#pragma unroll
    for (int nt = 0; nt < 4; nt++) {
#pragma unroll
      for (int j = 0; j < 4; j++) {
        const int row = m0 + wm + mt * 16 + lq * 4 + j;
        const int col = n0 + wn + nt * 16 + lm;
        C[(size_t)row * N_DIM + col] = acc[mt][nt][j] * s;
      }
    }
  }
}

extern "C" void kernel_launch(void* const* d_in, const int* in_sizes, int n_in,
                              void* d_out, int out_size, void* d_ws, size_t ws_size,
                              hipStream_t stream) {
  const float* x = (const float*)d_in[0];   // [B*S, 1024] fp32
  const float* w = (const float*)d_in[1];   // [1024, 1024] fp32
  float* out = (float*)d_out;               // [B*S, 1024] fp32
  const int M = in_sizes[0] / K_DIM;        // 65536

  hipLaunchKernelGGL(absum_kernel, dim3(256), dim3(256), 0, stream, w);
  hipLaunchKernelGGL(scale_kernel, dim3(1), dim3(256), 0, stream);
  hipLaunchKernelGGL(quant_kernel, dim3(1024), dim3(256), 0, stream, w);
  hipLaunchKernelGGL(bitlinear_gemm, dim3(N_DIM / 128, M / 128), dim3(256), 0, stream, x, out);
}

// Round 2
// 669.969 us; speedup vs baseline: 1.1623x; 1.1623x over previous
//
#include <hip/hip_runtime.h>
#include <stdint.h>

#define K_DIM 1024
#define N_DIM 1024
#define M_MAX 65536

typedef __attribute__((ext_vector_type(8))) __bf16 bf16x8;
typedef __attribute__((ext_vector_type(4))) float f32x4;

// Static device storage (fully rewritten every call; BSS, no load-time cost)
__device__ __align__(16) unsigned short g_wq[N_DIM * K_DIM];          // ternary W as bf16 bits
__device__ __align__(16) unsigned short g_xq[(size_t)M_MAX * K_DIM];  // x as bf16 bits (128 MB)
__device__ double g_partial[256];
__device__ float g_scale;

__device__ __forceinline__ unsigned int pack_bf16(float hi, float lo) {
  // (trunc_bf16(hi) << 16) | trunc_bf16(lo) in one v_perm_b32
  return __builtin_amdgcn_perm(__float_as_uint(hi), __float_as_uint(lo), 0x07060302u);
}

// ---- Kernel 1: partial sums of |w| (double accumulation, deterministic) ----
__global__ void absum_kernel(const float* __restrict__ w) {
  const int tid = threadIdx.x, bid = blockIdx.x;
  const float4* w4 = (const float4*)w;  // 262144 float4s total
  double s = 0.0;
#pragma unroll
  for (int i = 0; i < 4; i++) {
    float4 v = w4[bid * 1024 + i * 256 + tid];
    s += (double)fabsf(v.x) + (double)fabsf(v.y) + (double)fabsf(v.z) + (double)fabsf(v.w);
  }
#pragma unroll
  for (int o = 32; o > 0; o >>= 1) s += __shfl_down(s, o);
  __shared__ double sm[4];
  if ((tid & 63) == 0) sm[tid >> 6] = s;
  __syncthreads();
  if (tid == 0) g_partial[bid] = sm[0] + sm[1] + sm[2] + sm[3];
}

// ---- Kernel 2: final reduce -> scale = max(mean|w|, 1e-5) ----
__global__ void scale_kernel() {
  const int tid = threadIdx.x;
  double v = g_partial[tid];
#pragma unroll
  for (int o = 32; o > 0; o >>= 1) v += __shfl_down(v, o);
  __shared__ double sm[4];
  if ((tid & 63) == 0) sm[tid >> 6] = v;
  __syncthreads();
  if (tid == 0) {
    double total = sm[0] + sm[1] + sm[2] + sm[3];
    double mean = total * (1.0 / 1048576.0);  // exact pow2 divide
    g_scale = (float)fmax(mean, 1e-5);
  }
}

// ---- Kernel 3: quantize W -> ternary bf16 {-1,0,1} (exact in bf16) ----
__global__ void quant_kernel(const float* __restrict__ w) {
  const int idx = blockIdx.x * 256 + threadIdx.x;  // x4 floats
  const float s = g_scale;
  float4 v = ((const float4*)w)[idx];
  float q0 = fminf(1.f, fmaxf(-1.f, rintf(v.x / s)));
  float q1 = fminf(1.f, fmaxf(-1.f, rintf(v.y / s)));
  float q2 = fminf(1.f, fmaxf(-1.f, rintf(v.z / s)));
  float q3 = fminf(1.f, fmaxf(-1.f, rintf(v.w / s)));
  ushort4 o;
  o.x = (unsigned short)(__float_as_uint(q0) >> 16);
  o.y = (unsigned short)(__float_as_uint(q1) >> 16);
  o.z = (unsigned short)(__float_as_uint(q2) >> 16);
  o.w = (unsigned short)(__float_as_uint(q3) >> 16);
  ((ushort4*)g_wq)[idx] = o;
}

// ---- Kernel 4: convert x fp32 -> bf16 (truncation, streaming) ----
__global__ __launch_bounds__(256) void convert_x(const float* __restrict__ x) {
  const size_t t = (size_t)blockIdx.x * 256 + threadIdx.x;  // 8 floats per thread
  const float4* x4 = (const float4*)x;
  float4 a = x4[t * 2];
  float4 b = x4[t * 2 + 1];
  uint4 o;
  o.x = pack_bf16(a.y, a.x);
  o.y = pack_bf16(a.w, a.z);
  o.z = pack_bf16(b.y, b.x);
  o.w = pack_bf16(b.w, b.z);
  ((uint4*)g_xq)[t] = o;
}

// ---- Kernel 5: GEMM  C[M,N] = (Aq[M,K] @ Wq[N,K]^T) * scale ----
// m97 structure: 128x128 tile, BK=32, both operands via global_load_lds w=16,
// 4 waves (2x2), 4x4 MFMA 16x16x32 bf16 per wave.
__global__ __launch_bounds__(256) void bitlinear_gemm(float* __restrict__ C) {
  __shared__ __align__(16) unsigned short As[128 * 32];
  __shared__ __align__(16) unsigned short Bs[128 * 32];

  const int tid  = threadIdx.x;
  const int lane = tid & 63;
  const int wave = tid >> 6;
  const int wm   = (wave >> 1) * 64;
  const int wn   = (wave & 1) * 64;
  const int lm   = lane & 15;
  const int lq   = lane >> 4;

  // XCD-locality swizzle: blocks b, b+8, ..., b+56 (same XCD under %8
  // round-robin) share one A-panel and sweep its 8 n-tiles -> panel + all of
  // B stay L2-resident on that XCD.
  const int b  = blockIdx.x;
  const int mt = (b >> 6) * 8 + (b & 7);
  const int nt = (b >> 3) & 7;
  const int m0 = mt * 128;
  const int n0 = nt * 128;

  f32x4 acc[4][4];
#pragma unroll
  for (int i = 0; i < 4; i++)
#pragma unroll
    for (int j = 0; j < 4; j++) acc[i][j] = (f32x4){0.f, 0.f, 0.f, 0.f};

  // Staging (both operands): wave w covers rows [w*32, w*32+32);
  // one global_load_lds instr = 64 lanes x 16B = 16 rows x 64B.
  // lane l -> row + l/4, k-offset (l&3)*8 ushorts. LDS dest: base + lane*16B.
  const unsigned short* aptr =
      g_xq + (size_t)(m0 + wave * 32 + (lane >> 2)) * K_DIM + (lane & 3) * 8;
  const unsigned short* bptr =
      g_wq + (size_t)(n0 + wave * 32 + (lane >> 2)) * K_DIM + (lane & 3) * 8;

  for (int kc = 0; kc < K_DIM; kc += 32) {
    __builtin_amdgcn_global_load_lds(
        (const __attribute__((address_space(1))) unsigned int*)(aptr + kc),
        (__attribute__((address_space(3))) unsigned int*)&As[(wave * 32) * 32],
        16, 0, 0);
    __builtin_amdgcn_global_load_lds(
        (const __attribute__((address_space(1))) unsigned int*)(aptr + 16 * K_DIM + kc),
        (__attribute__((address_space(3))) unsigned int*)&As[(wave * 32 + 16) * 32],
        16, 0, 0);
    __builtin_amdgcn_global_load_lds(
        (const __attribute__((address_space(1))) unsigned int*)(bptr + kc),
        (__attribute__((address_space(3))) unsigned int*)&Bs[(wave * 32) * 32],
        16, 0, 0);
    __builtin_amdgcn_global_load_lds(
        (const __attribute__((address_space(1))) unsigned int*)(bptr + 16 * K_DIM + kc),
        (__attribute__((address_space(3))) unsigned int*)&Bs[(wave * 32 + 16) * 32],
        16, 0, 0);

    __syncthreads();  // compiler emits s_waitcnt vmcnt(0) before s_barrier

    const bf16x8* Ap = (const bf16x8*)&As[(wm + lm) * 32 + lq * 8];
    const bf16x8* Bp = (const bf16x8*)&Bs[(wn + lm) * 32 + lq * 8];
    bf16x8 af[4], bfr[4];
#pragma unroll
    for (int t = 0; t < 4; t++) {
      af[t]  = Ap[t * 64];  // +16 rows per tile
      bfr[t] = Bp[t * 64];
    }
#pragma unroll
    for (int i = 0; i < 4; i++)
#pragma unroll
      for (int j = 0; j < 4; j++)
        acc[i][j] =
            __builtin_amdgcn_mfma_f32_16x16x32_bf16(af[i], bfr[j], acc[i][j], 0, 0, 0);

    __syncthreads();
  }

  // Epilogue: C/D layout col=lane&15, row=(lane>>4)*4+j; apply scale here
  const float s = g_scale;
#pragma unroll
  for (int i = 0; i < 4; i++) {
#pragma unroll
    for (int j = 0; j < 4; j++) {
#pragma unroll
      for (int r = 0; r < 4; r++) {
        const int row = m0 + wm + i * 16 + lq * 4 + r;
        const int col = n0 + wn + j * 16 + lm;
        C[(size_t)row * N_DIM + col] = acc[i][j][r] * s;
      }
    }
  }
}

extern "C" void kernel_launch(void* const* d_in, const int* in_sizes, int n_in,
                              void* d_out, int out_size, void* d_ws, size_t ws_size,
                              hipStream_t stream) {
  const float* x = (const float*)d_in[0];   // [M, 1024] fp32
  const float* w = (const float*)d_in[1];   // [1024, 1024] fp32
  float* out = (float*)d_out;               // [M, 1024] fp32
  const int M = in_sizes[0] / K_DIM;        // 65536

  hipLaunchKernelGGL(absum_kernel, dim3(256), dim3(256), 0, stream, w);
  hipLaunchKernelGGL(scale_kernel, dim3(1), dim3(256), 0, stream);
  hipLaunchKernelGGL(quant_kernel, dim3(1024), dim3(256), 0, stream, w);
  hipLaunchKernelGGL(convert_x, dim3((unsigned)((size_t)M * K_DIM / 8 / 256)), dim3(256), 0,
                     stream, x);
  hipLaunchKernelGGL(bitlinear_gemm, dim3((unsigned)(((size_t)M / 128) * (N_DIM / 128))),
                     dim3(256), 0, stream, out);
}